// Round 6
// baseline (23532.800 us; speedup 1.0000x reference)
//
#include <hip/hip_runtime.h>

#define B_   8
#define C_   128
#define HW_  128
#define KW_  9
#define PROWS 136            // 4 zero-pad + 128 pos + 4 zero-pad
#define STRD 136             // LDS pos stride (elems) - bank-uniform
#define PBUF (PROWS * STRD)  // 18496 elems per buffer
#define THREADS 512          // 8 waves, 2/SIMD

typedef __bf16 bf16x8 __attribute__((ext_vector_type(8)));
typedef float  floatx4 __attribute__((ext_vector_type(4)));
typedef unsigned long long u64;

__device__ __forceinline__ unsigned short bf16rn(float f) {
  union { float f; unsigned u; } x; x.f = f;
  return (unsigned short)((x.u + 0x7fffu + ((x.u >> 16) & 1u)) >> 16);
}

// raw barrier: drain LDS ops only (no vmcnt drain - y stores have no in-kernel
// consumer; rule #18: sched_barrier fences MFMA hoisting past the waitcnt)
#define BARRIER_LGKM()                                         \
  do {                                                         \
    asm volatile("s_waitcnt lgkmcnt(0)" ::: "memory");         \
    __builtin_amdgcn_sched_barrier(0);                         \
    __builtin_amdgcn_s_barrier();                              \
    __builtin_amdgcn_sched_barrier(0);                         \
  } while (0)

// ---------------- prologue: x (B,C,H,W) -> y (B,H,W,C) fp32 ------------------
__global__ __launch_bounds__(256) void nchw_to_nhwc(const float* __restrict__ x,
                                                    float* __restrict__ y) {
  __shared__ float tile[32][33];
  const int blk = blockIdx.x;
  const int b = blk >> 7, h = blk & 127;
  const int tx = threadIdx.x & 31, ty = threadIdx.x >> 5;
  for (int t = 0; t < 16; ++t) {
    const int c0 = (t >> 2) * 32, w0 = (t & 3) * 32;
#pragma unroll
    for (int i = 0; i < 4; ++i) {
      const int c = c0 + ty + i * 8;
      tile[ty + i * 8][tx] = x[(((long)b * C_ + c) * HW_ + h) * HW_ + w0 + tx];
    }
    __syncthreads();
#pragma unroll
    for (int i = 0; i < 4; ++i) {
      const int w = w0 + ty + i * 8;
      y[(((long)b * HW_ + h) * HW_ + w) * C_ + c0 + tx] = tile[tx][ty + i * 8];
    }
    __syncthreads();
  }
}

// ---------------- epilogue: y (B,H,W,C) -> out (B,C,H,W) ---------------------
__global__ __launch_bounds__(256) void nhwc_to_nchw(const float* __restrict__ y,
                                                    float* __restrict__ out) {
  __shared__ float tile[32][33];
  const int blk = blockIdx.x;
  const int b = blk >> 7, h = blk & 127;
  const int tx = threadIdx.x & 31, ty = threadIdx.x >> 5;
  for (int t = 0; t < 16; ++t) {
    const int w0 = (t >> 2) * 32, c0 = (t & 3) * 32;
#pragma unroll
    for (int i = 0; i < 4; ++i) {
      const int w = w0 + ty + i * 8;
      tile[ty + i * 8][tx] = y[(((long)b * HW_ + h) * HW_ + w) * C_ + c0 + tx];
    }
    __syncthreads();
#pragma unroll
    for (int i = 0; i < 4; ++i) {
      const int c = c0 + ty + i * 8;
      out[(((long)b * C_ + c) * HW_ + h) * HW_ + w0 + tx] = tile[tx][ty + i * 8];
    }
    __syncthreads();
  }
}

// ---------------- per-direction scan: 8 blocks = 8 batches (FULL row) --------
// BLKS=1: each block owns the entire 128-pos row -> ZERO inter-block sync
// (no flags, no mailbox, no atomics, no halo corrections). Per scan step:
//   barrier A (lgkm) -> 2 passes of 4 pos-tiles:
//     {cur loads, 72 ds_read_b128 + 144 MFMA, ship acc[1-kh] to scratch,
//      barrier C (lgkm), finalize: reduce + relu + y store + nxt LDS write}
// Wave (kh, co2): Q=2 cout-tiles {co2*16, co2*16+64}, K-half c4 in {2kh,2kh+1};
// weights 144 VGPR/wave (proven 2 waves/SIMD shape).
// LDS: prow dbuf 2x136x136 bf16 (74KB) + scratch [4][2][8][64][4] f32 (64KB).
__global__ __launch_bounds__(THREADS, 2) void scnn_scan_dir(
    const float* __restrict__ Kg, float* __restrict__ y,
    const int posStride, const int sStride, const int s0, const int ds) {
  extern __shared__ unsigned char lds_raw[];
  unsigned short* prow = (unsigned short*)lds_raw;            // [2][PBUF]
  float* scr = (float*)(lds_raw + 2 * PBUF * 2);              // [4][2][8][64][4]
  const int tid = threadIdx.x;
  const int batch = blockIdx.x;
  const int lane = tid & 63;
  const int wave = tid >> 6;           // 0..7
  const int kh = wave >> 2;            // K-half: c4 in {2kh, 2kh+1}; ct finalized
  const int co2 = wave & 3;            // co-tile pair index
  const int l15 = lane & 15;
  const int quad = lane >> 4;
  const int ybase = batch * (HW_ * HW_ * C_);

  // zero both prow buffers (pad rows 0..3 / 132..135 must stay 0)
  for (int i = tid; i < 2 * PBUF / 4; i += THREADS)
    ((u64*)prow)[i] = 0ull;

  // persistent weights, A-operand (m = co_local): 2 ct x 9 kw x 2 c2 = 144 VGPRs
  bf16x8 wfrag[2][KW_][2];
#pragma unroll
  for (int ct = 0; ct < 2; ++ct) {
    const int co0 = co2 * 16 + ct * 64;
#pragma unroll
    for (int kw = 0; kw < KW_; ++kw)
#pragma unroll
      for (int c2 = 0; c2 < 2; ++c2) {
        const int c4 = kh * 2 + c2;
        union { bf16x8 v; unsigned short u[8]; } t;
#pragma unroll
        for (int j = 0; j < 8; ++j)
          t.u[j] = bf16rn(Kg[(kw * 128 + c4 * 32 + quad * 8 + j) * 128 + co0 + l15]);
        wfrag[ct][kw][c2] = t.v;
      }
  }
  __syncthreads();

  // init: load first row (s0), all 128 positions -> buffer 0 rows 4..131
  for (int i = tid; i < 128 * 32; i += THREADS) {
    const int pos = i >> 5, cg = i & 31;
    const floatx4 v =
        *(const floatx4*)&y[ybase + s0 * sStride + pos * posStride + cg * 4];
    union { u64 u; unsigned short s[4]; } t;
    t.s[0] = bf16rn(v[0]); t.s[1] = bf16rn(v[1]);
    t.s[2] = bf16rn(v[2]); t.s[3] = bf16rn(v[3]);
    *(u64*)&prow[(pos + 4) * STRD + cg * 4] = t.u;
  }
  __syncthreads();

  // lane-invariant output channel base: this wave finalizes ct == kh tile
  const int coMine = co2 * 16 + kh * 64 + quad * 4;

  int pb = 0;
#pragma unroll 1
  for (int s = 1; s < HW_; ++s) {
    const int srow = s0 + s * ds;
    const int rowb = ybase + srow * sStride;

    BARRIER_LGKM();  // A: row s-1 LDS writes + scratch reads complete
    const unsigned short* pc = prow + pb * PBUF;
    unsigned short* nxt = prow + (pb ^ 1) * PBUF;

#pragma unroll
    for (int h = 0; h < 2; ++h) {
      // cur-row loads for this pass (overlap the k-loop)
      floatx4 cur[4];
#pragma unroll
      for (int m = 0; m < 4; ++m) {
        const int pos = (h * 4 + m) * 16 + l15;
        cur[m] = *(const floatx4*)&y[rowb + pos * posStride + coMine];
      }

      floatx4 acc[2][4];
#pragma unroll
      for (int ct = 0; ct < 2; ++ct)
#pragma unroll
        for (int m = 0; m < 4; ++m)
          acc[ct][m] = floatx4{0.f, 0.f, 0.f, 0.f};

      // main k-loop: 4 pos-tiles x 9 kw x 2 c2 reads, each feeds 2 MFMAs
#pragma unroll
      for (int m = 0; m < 4; ++m) {
        const int n = h * 4 + m;
        const unsigned short* pbase = pc + (n * 16 + l15) * STRD + quad * 8;
#pragma unroll
        for (int kw = 0; kw < KW_; ++kw)
#pragma unroll
          for (int c2 = 0; c2 < 2; ++c2) {
            const int c4 = kh * 2 + c2;
            const bf16x8 b0 = *(const bf16x8*)(pbase + kw * STRD + c4 * 32);
            acc[0][m] = __builtin_amdgcn_mfma_f32_16x16x32_bf16(
                wfrag[0][kw][c2], b0, acc[0][m], 0, 0, 0);
            acc[1][m] = __builtin_amdgcn_mfma_f32_16x16x32_bf16(
                wfrag[1][kw][c2], b0, acc[1][m], 0, 0, 0);
          }
      }

      // ship partner-half partials (slot n is globally unique -> no reuse race)
#pragma unroll
      for (int m = 0; m < 4; ++m) {
        const int n = h * 4 + m;
        *(floatx4*)&scr[(((co2 * 2 + (1 - kh)) * 8 + n) * 64 + lane) * 4] =
            acc[1 - kh][m];
      }
      BARRIER_LGKM();  // C_h: partials visible

      // finalize: reduce, o = cur + relu(a), y store (no drain needed), nxt LDS
#pragma unroll
      for (int m = 0; m < 4; ++m) {
        const int n = h * 4 + m;
        const int pos = n * 16 + l15;
        const floatx4 pz =
            *(const floatx4*)&scr[(((co2 * 2 + kh) * 8 + n) * 64 + lane) * 4];
        const floatx4 a = acc[kh][m] + pz;
        floatx4 o;
        o[0] = cur[m][0] + (a[0] > 0.f ? a[0] : 0.f);
        o[1] = cur[m][1] + (a[1] > 0.f ? a[1] : 0.f);
        o[2] = cur[m][2] + (a[2] > 0.f ? a[2] : 0.f);
        o[3] = cur[m][3] + (a[3] > 0.f ? a[3] : 0.f);
        *(floatx4*)&y[rowb + pos * posStride + coMine] = o;
        union { u64 u; unsigned short s[4]; } t;
        t.s[0] = bf16rn(o[0]); t.s[1] = bf16rn(o[1]);
        t.s[2] = bf16rn(o[2]); t.s[3] = bf16rn(o[3]);
        *(u64*)&nxt[(pos + 4) * STRD + coMine] = t.u;
      }
    }
    pb ^= 1;
  }
}

// ---------------- launcher ---------------------------------------------------
extern "C" void kernel_launch(void* const* d_in, const int* in_sizes, int n_in,
                              void* d_out, int out_size, void* d_ws, size_t ws_size,
                              hipStream_t stream) {
  const float* x = (const float*)d_in[0];
  const float* K[4] = {(const float*)d_in[1], (const float*)d_in[2],
                       (const float*)d_in[3], (const float*)d_in[4]};
  float* out = (float*)d_out;
  float* y = (float*)d_ws;  // 67,108,864 B

  // dynamic LDS: prow dbuf 73,984 B + scratch 65,536 B = 139,520 B
  const int LDS_BYTES = 2 * PBUF * 2 + 4 * 2 * 8 * 64 * 4 * 4;
  static bool attrDone = false;
  if (!attrDone) {
    hipFuncSetAttribute(reinterpret_cast<const void*>(scnn_scan_dir),
                        hipFuncAttributeMaxDynamicSharedMemorySize, LDS_BYTES);
    attrDone = true;
  }

  nchw_to_nhwc<<<B_ * HW_, 256, 0, stream>>>(x, y);

  const int PS[4] = {C_, C_, HW_ * C_, HW_ * C_};
  const int SS[4] = {HW_ * C_, HW_ * C_, C_, C_};
  const int S0[4] = {0, HW_ - 1, 0, HW_ - 1};
  const int DS[4] = {1, -1, 1, -1};
  for (int d = 0; d < 4; ++d)
    scnn_scan_dir<<<B_, THREADS, LDS_BYTES, stream>>>(K[d], y, PS[d], SS[d],
                                                      S0[d], DS[d]);

  nhwc_to_nchw<<<B_ * HW_, 256, 0, stream>>>(y, out);
}